// Round 7
// baseline (236.263 us; speedup 1.0000x reference)
//
#include <hip/hip_runtime.h>
#include <hip/hip_bf16.h>

#define N_NODES 50000
#define N_EDGES 800000
#define DIM 256      // input feature dim = K
#define QKDIM 256    // packed q|k per node (fp8: 256 B/row)
#define NB_T  391    // target buckets: d0 >> 7 (128 nodes per bucket)
#define CAP   8192   // per-bucket record capacity (mean 4092, sigma ~64)
#define ITEMS (2 * N_EDGES)
#define IPB   4096   // items per prep_bin block (391 * 4096 >= 1.6M)
// pre = (0.5/H) * sum_A (q_s k_d + q_d k_s) = (full rotated 256-dot)/16

typedef __bf16 bfrag  __attribute__((ext_vector_type(8)));
typedef __bf16 bf4    __attribute__((ext_vector_type(4)));
typedef float  ffrag  __attribute__((ext_vector_type(4)));
typedef float  f2     __attribute__((ext_vector_type(2)));
typedef float  f4v    __attribute__((ext_vector_type(4)));

#define EP_PITCH 272   // epilogue LDS byte pitch (256+16)

// ---------------- prep_bin: W' fp32->bf16 + bin d0 items by target bucket ----
// Binning: per-block LDS hist -> one global chunk-reservation atomic per
// (block,bucket) (~150K atomics total) -> packed records (local<<20 | edge).
__global__ __launch_bounds__(256) void prep_bin(
    const float* __restrict__ Wq, const float* __restrict__ Wk,
    __bf16* __restrict__ Wb,
    const int* __restrict__ d0, unsigned int* __restrict__ rec,
    int* __restrict__ cur)
{
    __shared__ int lcnt[NB_T];
    __shared__ int lbase[NB_T];
    const int tid = threadIdx.x;
    const int gtid = blockIdx.x * 256 + tid;

    // ---- W convert (first 16384 gtids cover 65536 floats) ----
    const int i4 = gtid * 4;
    if (i4 < 65536) {
        const float* s = (i4 < 32768) ? (Wq + i4) : (Wk + (i4 - 32768));
        const float4 v = *(const float4*)s;
        bf4 o;
        o[0] = (__bf16)v.x; o[1] = (__bf16)v.y; o[2] = (__bf16)v.z; o[3] = (__bf16)v.w;
        *(bf4*)(Wb + i4) = o;
    }

    // ---- pass 1: count this block's items per bucket ----
    for (int b = tid; b < NB_T; b += 256) lcnt[b] = 0;
    __syncthreads();
    const int base = blockIdx.x * IPB;
    int tg[16];
    #pragma unroll
    for (int r = 0; r < 16; ++r) {
        const int i = base + r * 256 + tid;
        tg[r] = (i < ITEMS) ? d0[i] : -1;
        if (tg[r] >= 0) atomicAdd(&lcnt[tg[r] >> 7], 1);
    }
    __syncthreads();

    // ---- reserve contiguous chunks in each bucket ----
    for (int b = tid; b < NB_T; b += 256) {
        const int c = lcnt[b];
        lbase[b] = c ? atomicAdd(&cur[b], c) : 0;
    }
    __syncthreads();
    for (int b = tid; b < NB_T; b += 256) lcnt[b] = 0;   // reuse as offset
    __syncthreads();

    // ---- pass 2: write packed records ----
    #pragma unroll
    for (int r = 0; r < 16; ++r) {
        if (tg[r] >= 0) {
            const int i = base + r * 256 + tid;
            const int b = tg[r] >> 7;
            const int off = atomicAdd(&lcnt[b], 1);
            rec[(size_t)b * CAP + lbase[b] + off] =
                ((unsigned int)(tg[r] & 127) << 20) | (unsigned int)(i >> 1);
        }
    }
}

// ---------------- Projection via MFMA bf16 (unchanged, known-good) ----------
__global__ __launch_bounds__(256) void proj_mfma(
    const float* __restrict__ x,
    const __bf16* __restrict__ Wb,
    const float* __restrict__ bq, const float* __restrict__ bk,
    unsigned char* __restrict__ qk8)
{
    __shared__ __bf16 As[64 * 256];   // 32 KB, fragment-order; reused by epilogue

    const int tid  = threadIdx.x;
    const int wv   = tid >> 6;
    const int lane = tid & 63;
    const int m    = lane & 15;
    const int q    = lane >> 4;
    const int mbase = blockIdx.x * 64;

    {
        const int srow = tid >> 2;
        const int c4   = tid & 3;
        int grow = mbase + srow;
        grow = grow < N_NODES ? grow : N_NODES - 1;
        const float* xp = x + (size_t)grow * DIM;
        const int mt_ = srow >> 4, m_ = srow & 15;
        #pragma unroll
        for (int i = 0; i < 16; ++i) {
            const int k = c4 * 4 + 16 * i;
            const f4v v = __builtin_nontemporal_load((const f4v*)(xp + k));
            bf4 o;
            o[0] = (__bf16)v[0]; o[1] = (__bf16)v[1];
            o[2] = (__bf16)v[2]; o[3] = (__bf16)v[3];
            const int seg = (k >> 5) * 4 + mt_;
            const int ln  = ((k >> 3) & 3) * 16 + m_;
            *(bf4*)(As + seg * 512 + ln * 8 + (k & 7)) = o;
        }
    }
    __syncthreads();

    ffrag acc[4][4] = {};

    #pragma unroll
    for (int h = 0; h < 2; ++h) {
        bfrag b[4][4];
        #pragma unroll
        for (int sp = 0; sp < 4; ++sp)
            #pragma unroll
            for (int nt = 0; nt < 4; ++nt) {
                const int col = wv * 64 + nt * 16 + m;
                b[sp][nt] = *(const bfrag*)(Wb + (size_t)col * DIM
                                            + 32 * (4 * h + sp) + 8 * q);
            }
        #pragma unroll
        for (int sp = 0; sp < 4; ++sp) {
            bfrag a[4];
            #pragma unroll
            for (int mt = 0; mt < 4; ++mt)
                a[mt] = *(const bfrag*)(As + ((4 * h + sp) * 4 + mt) * 512 + lane * 8);
            #pragma unroll
            for (int mt = 0; mt < 4; ++mt)
                #pragma unroll
                for (int nt = 0; nt < 4; ++nt)
                    acc[mt][nt] = __builtin_amdgcn_mfma_f32_16x16x32_bf16(
                                      a[mt], b[sp][nt], acc[mt][nt], 0, 0, 0);
        }
    }

    __syncthreads();
    unsigned char* ep = (unsigned char*)As;
    #pragma unroll
    for (int nt = 0; nt < 4; ++nt) {
        const int col  = wv * 64 + nt * 16 + m;
        const float bias = (col < 128) ? bq[col] : bk[col - 128];
        #pragma unroll
        for (int mt = 0; mt < 4; ++mt) {
            #pragma unroll
            for (int r = 0; r < 4; ++r) {
                const int rl = mt * 16 + q * 4 + r;
                const float v = acc[mt][nt][r] + bias;
                const int pk = __builtin_amdgcn_cvt_pk_fp8_f32(v, v, 0, false);
                ep[rl * EP_PITCH + col] = (unsigned char)(pk & 0xFF);
            }
        }
    }
    __syncthreads();
    {
        const int rl = tid >> 2;
        const int ch = tid & 3;
        const int grow = mbase + rl;
        if (grow < N_NODES) {
            const uint4* s4 = (const uint4*)(ep + rl * EP_PITCH + ch * 64);
            const uint4 t0 = s4[0], t1 = s4[1], t2 = s4[2], t3 = s4[3];
            uint4* g = (uint4*)(qk8 + (size_t)grow * QKDIM + ch * 64);
            g[0] = t0; g[1] = t1; g[2] = t2; g[3] = t3;
        }
    }
}

// ---------------- Edge scoring: gather + dot + exp, NO atomics --------------
// 4 lanes per edge-slot, 16 slots/wave, TWO edges per slot (e, e+16).
// All 16 gather loads issued before any compute -> 2x MLP in the
// latency-per-wave regime (retry of R2's idea, valid now atomics are gone).
// Lane j: src bytes [64j,+64); dst bytes 64*((j+2)&3).  [R4 known-good]
__global__ __launch_bounds__(256, 4) void edge_compute(
    const unsigned char* __restrict__ qk8,
    const int* __restrict__ edge_index,   // [2][E]
    float* __restrict__ out)              // writes diagA1 = out[N..N+E)
{
    const int wave = (blockIdx.x * blockDim.x + threadIdx.x) >> 6;
    const int lane = threadIdx.x & 63;
    const int g = lane >> 2;              // edge slot within wave (0..15)
    const int j = lane & 3;               // lane within edge
    const int e0 = wave * 32 + g;         // 800000 = 25000*32, no tail
    const int e1 = e0 + 16;

    const int src0 = __builtin_nontemporal_load(edge_index + e0);
    const int dst0 = __builtin_nontemporal_load(edge_index + N_EDGES + e0);
    const int src1 = __builtin_nontemporal_load(edge_index + e1);
    const int dst1 = __builtin_nontemporal_load(edge_index + N_EDGES + e1);

    const uint4* rs0 = (const uint4*)(qk8 + (size_t)src0 * QKDIM + 64 * j);
    const uint4* rd0 = (const uint4*)(qk8 + (size_t)dst0 * QKDIM + 64 * ((j + 2) & 3));
    const uint4* rs1 = (const uint4*)(qk8 + (size_t)src1 * QKDIM + 64 * j);
    const uint4* rd1 = (const uint4*)(qk8 + (size_t)dst1 * QKDIM + 64 * ((j + 2) & 3));

    // issue ALL 16 loads before any compute
    uint4 a0[4], b0[4], a1[4], b1[4];
    #pragma unroll
    for (int i = 0; i < 4; ++i) a0[i] = rs0[i];
    #pragma unroll
    for (int i = 0; i < 4; ++i) b0[i] = rd0[i];
    #pragma unroll
    for (int i = 0; i < 4; ++i) a1[i] = rs1[i];
    #pragma unroll
    for (int i = 0; i < 4; ++i) b1[i] = rd1[i];

    f2 acc0 = {0.f, 0.f};
    #pragma unroll
    for (int i = 0; i < 4; ++i) {
        const unsigned int* ua = (const unsigned int*)&a0[i];
        const unsigned int* ub = (const unsigned int*)&b0[i];
        #pragma unroll
        for (int t = 0; t < 4; ++t) {
            const f2 x0 = __builtin_amdgcn_cvt_pk_f32_fp8(ua[t], false);
            const f2 y0 = __builtin_amdgcn_cvt_pk_f32_fp8(ub[t], false);
            const f2 x1 = __builtin_amdgcn_cvt_pk_f32_fp8(ua[t], true);
            const f2 y1 = __builtin_amdgcn_cvt_pk_f32_fp8(ub[t], true);
            acc0 += x0 * y0;
            acc0 += x1 * y1;
        }
    }
    f2 acc1 = {0.f, 0.f};
    #pragma unroll
    for (int i = 0; i < 4; ++i) {
        const unsigned int* ua = (const unsigned int*)&a1[i];
        const unsigned int* ub = (const unsigned int*)&b1[i];
        #pragma unroll
        for (int t = 0; t < 4; ++t) {
            const f2 x0 = __builtin_amdgcn_cvt_pk_f32_fp8(ua[t], false);
            const f2 y0 = __builtin_amdgcn_cvt_pk_f32_fp8(ub[t], false);
            const f2 x1 = __builtin_amdgcn_cvt_pk_f32_fp8(ua[t], true);
            const f2 y1 = __builtin_amdgcn_cvt_pk_f32_fp8(ub[t], true);
            acc1 += x0 * y0;
            acc1 += x1 * y1;
        }
    }

    float p0 = acc0[0] + acc0[1];
    p0 += __shfl_xor(p0, 1, 64);
    p0 += __shfl_xor(p0, 2, 64);
    float p1 = acc1[0] + acc1[1];
    p1 += __shfl_xor(p1, 1, 64);
    p1 += __shfl_xor(p1, 2, 64);

    if (j == 0) {
        out[N_NODES + e0] = __expf(p0 * 0.0625f);  // /16 = 0.5*mean over 8 heads
        out[N_NODES + e1] = __expf(p1 * 0.0625f);
    }
}

// ---------------- phase_scatter: per-bucket LDS aggregation -> plain stores -
// Block b owns nodes [128b, 128b+128): reads its bucket's records, gathers
// val[e] from diagA1 (L2-resident), LDS-atomicAdd, then unique-writer stores.
// Zero global atomics; out[0..N) needs no pre-zeroing.
__global__ __launch_bounds__(1024) void phase_scatter(
    const unsigned int* __restrict__ rec, const int* __restrict__ cur,
    float* __restrict__ out)
{
    __shared__ float acc[128];
    const int b = blockIdx.x;
    const int tid = threadIdx.x;
    if (tid < 128) acc[tid] = 0.f;
    __syncthreads();

    const int cnt = cur[b];
    const unsigned int* rb = rec + (size_t)b * CAP;
    for (int i = tid; i < cnt; i += 1024) {
        const unsigned int r = rb[i];
        const float v = out[N_NODES + (r & 0xFFFFF)];
        atomicAdd(&acc[r >> 20], v);
    }
    __syncthreads();

    if (tid < 128) {
        const int n = b * 128 + tid;
        if (n < N_NODES) out[n] = acc[tid];
    }
}

extern "C" void kernel_launch(void* const* d_in, const int* in_sizes, int n_in,
                              void* d_out, int out_size, void* d_ws, size_t ws_size,
                              hipStream_t stream) {
    const float* x  = (const float*)d_in[0];
    const float* Wq = (const float*)d_in[1];
    const float* bq = (const float*)d_in[2];
    const float* Wk = (const float*)d_in[3];
    const float* bk = (const float*)d_in[4];
    const int* edge_index = (const int*)d_in[5];
    const int* d0 = (const int*)d_in[6] + 2 * N_EDGES;  // row 1 of d0_index
    float* out = (float*)d_out;

    char* w = (char*)d_ws;
    unsigned char* qk8 = (unsigned char*)w;  w += (size_t)N_NODES * QKDIM;  // 12.8 MB
    __bf16* Wb = (__bf16*)w;                 w += 131072;                   // 128 KB
    unsigned int* rec = (unsigned int*)w;    w += (size_t)NB_T * CAP * 4;   // 12.8 MB
    int* cur = (int*)w;                      w += 2048;

    hipMemsetAsync(cur, 0, NB_T * sizeof(int), stream);
    prep_bin<<<NB_T, 256, 0, stream>>>(Wq, Wk, Wb, d0, rec, cur);
    proj_mfma<<<(N_NODES + 63) / 64, 256, 0, stream>>>(x, Wb, bq, bk, qk8);
    edge_compute<<<N_EDGES / 128, 256, 0, stream>>>(qk8, edge_index, out);
    phase_scatter<<<NB_T, 1024, 0, stream>>>(rec, cur, out);
}

// Round 8
// 219.129 us; speedup vs baseline: 1.0782x; 1.0782x over previous
//
#include <hip/hip_runtime.h>
#include <hip/hip_bf16.h>

#define N_NODES 50000
#define N_EDGES 800000
#define DIM 256      // input feature dim = K
#define QKDIM 256    // packed q|k per node (fp8: 256 B/row)
#define NB_T  391    // buckets: node >> 7 (128 nodes per bucket)
#define CAP   6144   // d0 bucket capacity (mean 4092, sigma ~64 -> +32 sigma)
#define CAP2  2816   // edge src-bucket capacity (mean 2046, sigma ~45 -> +17 sigma)
#define BPB2  44     // edge blocks per bucket (CAP2/64)
#define ITEMS (2 * N_EDGES)
#define IPB   4096   // d0 items per prep_bin block
#define EPB2  2048   // edges per prep_bin block (391*2048 >= 800000)
// pre = (0.5/H) * sum_A (q_s k_d + q_d k_s) = (full rotated 256-dot)/16

typedef __bf16 bfrag  __attribute__((ext_vector_type(8)));
typedef __bf16 bf4    __attribute__((ext_vector_type(4)));
typedef float  ffrag  __attribute__((ext_vector_type(4)));
typedef float  f2     __attribute__((ext_vector_type(2)));
typedef float  f4v    __attribute__((ext_vector_type(4)));

#define EP_PITCH 272   // epilogue LDS byte pitch (256+16)

// ---------------- prep_bin: W' convert + bin d0 items + bin edges by src ----
// Chunk-reservation binning: LDS hist -> one global atomic per (block,bucket).
__global__ __launch_bounds__(256) void prep_bin(
    const float* __restrict__ Wq, const float* __restrict__ Wk,
    __bf16* __restrict__ Wb,
    const int* __restrict__ d0, unsigned int* __restrict__ rec,
    int* __restrict__ cur,
    const int* __restrict__ edge_index, uint2* __restrict__ rec2,
    int* __restrict__ cur2, int do_edges)
{
    __shared__ int lcnt[NB_T];
    __shared__ int lbase[NB_T];
    const int tid = threadIdx.x;
    const int gtid = blockIdx.x * 256 + tid;

    // ---- W convert (first 16384 gtids cover 65536 floats) ----
    const int i4 = gtid * 4;
    if (i4 < 65536) {
        const float* s = (i4 < 32768) ? (Wq + i4) : (Wk + (i4 - 32768));
        const float4 v = *(const float4*)s;
        bf4 o;
        o[0] = (__bf16)v.x; o[1] = (__bf16)v.y; o[2] = (__bf16)v.z; o[3] = (__bf16)v.w;
        *(bf4*)(Wb + i4) = o;
    }

    // ================= phase A: bin d0 items by target bucket ==============
    for (int b = tid; b < NB_T; b += 256) lcnt[b] = 0;
    __syncthreads();
    const int base = blockIdx.x * IPB;
    int tg[16];
    #pragma unroll
    for (int r = 0; r < 16; ++r) {
        const int i = base + r * 256 + tid;
        tg[r] = (i < ITEMS) ? d0[i] : -1;
        if (tg[r] >= 0) atomicAdd(&lcnt[tg[r] >> 7], 1);
    }
    __syncthreads();
    for (int b = tid; b < NB_T; b += 256) {
        const int c = lcnt[b];
        lbase[b] = c ? atomicAdd(&cur[b], c) : 0;
    }
    __syncthreads();
    for (int b = tid; b < NB_T; b += 256) lcnt[b] = 0;   // reuse as offset
    __syncthreads();
    #pragma unroll
    for (int r = 0; r < 16; ++r) {
        if (tg[r] >= 0) {
            const int i = base + r * 256 + tid;
            const int b = tg[r] >> 7;
            const int off = atomicAdd(&lcnt[b], 1);
            rec[(size_t)b * CAP + lbase[b] + off] =
                ((unsigned int)(tg[r] & 127) << 20) | (unsigned int)(i >> 1);
        }
    }

    if (!do_edges) return;

    // ================= phase B: bin edges by src bucket ====================
    __syncthreads();
    for (int b = tid; b < NB_T; b += 256) lcnt[b] = 0;
    __syncthreads();
    const int ebase = blockIdx.x * EPB2;
    int es[8], ed[8];
    #pragma unroll
    for (int r = 0; r < 8; ++r) {
        const int e = ebase + r * 256 + tid;
        es[r] = (e < N_EDGES) ? edge_index[e] : -1;
        ed[r] = (e < N_EDGES) ? edge_index[N_EDGES + e] : 0;
        if (es[r] >= 0) atomicAdd(&lcnt[es[r] >> 7], 1);
    }
    __syncthreads();
    for (int b = tid; b < NB_T; b += 256) {
        const int c = lcnt[b];
        lbase[b] = c ? atomicAdd(&cur2[b], c) : 0;
    }
    __syncthreads();
    for (int b = tid; b < NB_T; b += 256) lcnt[b] = 0;
    __syncthreads();
    #pragma unroll
    for (int r = 0; r < 8; ++r) {
        if (es[r] >= 0) {
            const int e = ebase + r * 256 + tid;
            const int b = es[r] >> 7;
            const int off = atomicAdd(&lcnt[b], 1);
            const unsigned long long pk = (unsigned long long)(unsigned)es[r]
                | ((unsigned long long)(unsigned)ed[r] << 17)
                | ((unsigned long long)(unsigned)e << 34);
            rec2[(size_t)b * CAP2 + lbase[b] + off] =
                make_uint2((unsigned)pk, (unsigned)(pk >> 32));
        }
    }
}

// ---------------- Projection via MFMA bf16 (unchanged, known-good) ----------
__global__ __launch_bounds__(256) void proj_mfma(
    const float* __restrict__ x,
    const __bf16* __restrict__ Wb,
    const float* __restrict__ bq, const float* __restrict__ bk,
    unsigned char* __restrict__ qk8)
{
    __shared__ __bf16 As[64 * 256];   // 32 KB, fragment-order; reused by epilogue

    const int tid  = threadIdx.x;
    const int wv   = tid >> 6;
    const int lane = tid & 63;
    const int m    = lane & 15;
    const int q    = lane >> 4;
    const int mbase = blockIdx.x * 64;

    {
        const int srow = tid >> 2;
        const int c4   = tid & 3;
        int grow = mbase + srow;
        grow = grow < N_NODES ? grow : N_NODES - 1;
        const float* xp = x + (size_t)grow * DIM;
        const int mt_ = srow >> 4, m_ = srow & 15;
        #pragma unroll
        for (int i = 0; i < 16; ++i) {
            const int k = c4 * 4 + 16 * i;
            const f4v v = __builtin_nontemporal_load((const f4v*)(xp + k));
            bf4 o;
            o[0] = (__bf16)v[0]; o[1] = (__bf16)v[1];
            o[2] = (__bf16)v[2]; o[3] = (__bf16)v[3];
            const int seg = (k >> 5) * 4 + mt_;
            const int ln  = ((k >> 3) & 3) * 16 + m_;
            *(bf4*)(As + seg * 512 + ln * 8 + (k & 7)) = o;
        }
    }
    __syncthreads();

    ffrag acc[4][4] = {};

    #pragma unroll
    for (int h = 0; h < 2; ++h) {
        bfrag b[4][4];
        #pragma unroll
        for (int sp = 0; sp < 4; ++sp)
            #pragma unroll
            for (int nt = 0; nt < 4; ++nt) {
                const int col = wv * 64 + nt * 16 + m;
                b[sp][nt] = *(const bfrag*)(Wb + (size_t)col * DIM
                                            + 32 * (4 * h + sp) + 8 * q);
            }
        #pragma unroll
        for (int sp = 0; sp < 4; ++sp) {
            bfrag a[4];
            #pragma unroll
            for (int mt = 0; mt < 4; ++mt)
                a[mt] = *(const bfrag*)(As + ((4 * h + sp) * 4 + mt) * 512 + lane * 8);
            #pragma unroll
            for (int mt = 0; mt < 4; ++mt)
                #pragma unroll
                for (int nt = 0; nt < 4; ++nt)
                    acc[mt][nt] = __builtin_amdgcn_mfma_f32_16x16x32_bf16(
                                      a[mt], b[sp][nt], acc[mt][nt], 0, 0, 0);
        }
    }

    __syncthreads();
    unsigned char* ep = (unsigned char*)As;
    #pragma unroll
    for (int nt = 0; nt < 4; ++nt) {
        const int col  = wv * 64 + nt * 16 + m;
        const float bias = (col < 128) ? bq[col] : bk[col - 128];
        #pragma unroll
        for (int mt = 0; mt < 4; ++mt) {
            #pragma unroll
            for (int r = 0; r < 4; ++r) {
                const int rl = mt * 16 + q * 4 + r;
                const float v = acc[mt][nt][r] + bias;
                const int pk = __builtin_amdgcn_cvt_pk_fp8_f32(v, v, 0, false);
                ep[rl * EP_PITCH + col] = (unsigned char)(pk & 0xFF);
            }
        }
    }
    __syncthreads();
    {
        const int rl = tid >> 2;
        const int ch = tid & 3;
        const int grow = mbase + rl;
        if (grow < N_NODES) {
            const uint4* s4 = (const uint4*)(ep + rl * EP_PITCH + ch * 64);
            const uint4 t0 = s4[0], t1 = s4[1], t2 = s4[2], t3 = s4[3];
            uint4* g = (uint4*)(qk8 + (size_t)grow * QKDIM + ch * 64);
            g[0] = t0; g[1] = t1; g[2] = t2; g[3] = t3;
        }
    }
}

// ---------------- Edge scoring on src-bucketed records, NO atomics ---------
// Block = (bucket b, chunk c): 64 slots of bucket b. All srcs within a 32 KB
// qk8 window -> L1/L2-hot; only dst side stays random. 1 edge per 4-lane
// group (R6 known-good form; 2x batching regressed twice: R2, R7).
__global__ __launch_bounds__(256) void edge_compute(
    const unsigned char* __restrict__ qk8,
    const uint2* __restrict__ rec2, const int* __restrict__ cur2,
    float* __restrict__ out)              // writes diagA1 = out[N..N+E)
{
    const int b = blockIdx.x / BPB2;
    const int c = blockIdx.x - b * BPB2;
    const int lane = threadIdx.x & 63;
    const int g = lane >> 2;              // edge group within wave (0..15)
    const int j = lane & 3;               // lane within edge
    const int idx = c * 64 + ((threadIdx.x >> 6) << 4) + g;

    if (idx >= cur2[b]) return;           // uniform across the 4-lane group

    const uint2 rw = rec2[(size_t)b * CAP2 + idx];
    const unsigned long long pk = ((unsigned long long)rw.y << 32) | rw.x;
    const int src = (int)(pk & 0x1FFFF);
    const int dst = (int)((pk >> 17) & 0x1FFFF);
    const int e   = (int)(pk >> 34);

    const uint4* rs = (const uint4*)(qk8 + (size_t)src * QKDIM + 64 * j);
    const uint4* rd = (const uint4*)(qk8 + (size_t)dst * QKDIM + 64 * ((j + 2) & 3));

    uint4 a[4], bb[4];
    #pragma unroll
    for (int i = 0; i < 4; ++i) { a[i] = rs[i]; bb[i] = rd[i]; }

    f2 acc = {0.f, 0.f};
    #pragma unroll
    for (int i = 0; i < 4; ++i) {
        const unsigned int* ua = (const unsigned int*)&a[i];
        const unsigned int* ub = (const unsigned int*)&bb[i];
        #pragma unroll
        for (int t = 0; t < 4; ++t) {
            const f2 x0 = __builtin_amdgcn_cvt_pk_f32_fp8(ua[t], false);
            const f2 y0 = __builtin_amdgcn_cvt_pk_f32_fp8(ub[t], false);
            const f2 x1 = __builtin_amdgcn_cvt_pk_f32_fp8(ua[t], true);
            const f2 y1 = __builtin_amdgcn_cvt_pk_f32_fp8(ub[t], true);
            acc += x0 * y0;
            acc += x1 * y1;
        }
    }
    float p = acc[0] + acc[1];
    p += __shfl_xor(p, 1, 64);
    p += __shfl_xor(p, 2, 64);

    if (j == 0)
        out[N_NODES + e] = __expf(p * 0.0625f);   // /16 = 0.5 * mean over 8 heads
}

// ---------------- fallback: direct edge kernel (R6 form) --------------------
__global__ __launch_bounds__(256) void edge_direct(
    const unsigned char* __restrict__ qk8,
    const int* __restrict__ edge_index,
    float* __restrict__ out)
{
    const int wave = (blockIdx.x * blockDim.x + threadIdx.x) >> 6;
    const int lane = threadIdx.x & 63;
    const int g = lane >> 2, j = lane & 3;
    const int e = wave * 16 + g;

    const int src = __builtin_nontemporal_load(edge_index + e);
    const int dst = __builtin_nontemporal_load(edge_index + N_EDGES + e);

    const uint4* rs = (const uint4*)(qk8 + (size_t)src * QKDIM + 64 * j);
    const uint4* rd = (const uint4*)(qk8 + (size_t)dst * QKDIM + 64 * ((j + 2) & 3));

    uint4 a[4], b[4];
    #pragma unroll
    for (int i = 0; i < 4; ++i) { a[i] = rs[i]; b[i] = rd[i]; }

    f2 acc = {0.f, 0.f};
    #pragma unroll
    for (int i = 0; i < 4; ++i) {
        const unsigned int* ua = (const unsigned int*)&a[i];
        const unsigned int* ub = (const unsigned int*)&b[i];
        #pragma unroll
        for (int t = 0; t < 4; ++t) {
            const f2 x0 = __builtin_amdgcn_cvt_pk_f32_fp8(ua[t], false);
            const f2 y0 = __builtin_amdgcn_cvt_pk_f32_fp8(ub[t], false);
            const f2 x1 = __builtin_amdgcn_cvt_pk_f32_fp8(ua[t], true);
            const f2 y1 = __builtin_amdgcn_cvt_pk_f32_fp8(ub[t], true);
            acc += x0 * y0;
            acc += x1 * y1;
        }
    }
    float p = acc[0] + acc[1];
    p += __shfl_xor(p, 1, 64);
    p += __shfl_xor(p, 2, 64);

    if (j == 0)
        out[N_NODES + e] = __expf(p * 0.0625f);
}

// ---------------- phase_scatter: per-bucket LDS aggregation -> plain stores -
__global__ __launch_bounds__(1024) void phase_scatter(
    const unsigned int* __restrict__ rec, const int* __restrict__ cur,
    float* __restrict__ out)
{
    __shared__ float acc[128];
    const int b = blockIdx.x;
    const int tid = threadIdx.x;
    if (tid < 128) acc[tid] = 0.f;
    __syncthreads();

    const int cnt = cur[b];
    const unsigned int* rb = rec + (size_t)b * CAP;
    for (int i = tid; i < cnt; i += 1024) {
        const unsigned int r = rb[i];
        const float v = out[N_NODES + (r & 0xFFFFF)];
        atomicAdd(&acc[r >> 20], v);
    }
    __syncthreads();

    if (tid < 128) {
        const int n = b * 128 + tid;
        if (n < N_NODES) out[n] = acc[tid];
    }
}

extern "C" void kernel_launch(void* const* d_in, const int* in_sizes, int n_in,
                              void* d_out, int out_size, void* d_ws, size_t ws_size,
                              hipStream_t stream) {
    const float* x  = (const float*)d_in[0];
    const float* Wq = (const float*)d_in[1];
    const float* bq = (const float*)d_in[2];
    const float* Wk = (const float*)d_in[3];
    const float* bk = (const float*)d_in[4];
    const int* edge_index = (const int*)d_in[5];
    const int* d0 = (const int*)d_in[6] + 2 * N_EDGES;  // row 1 of d0_index
    float* out = (float*)d_out;

    char* w = (char*)d_ws;
    unsigned char* qk8 = (unsigned char*)w;  w += (size_t)N_NODES * QKDIM;  // 12.8 MB
    __bf16* Wb = (__bf16*)w;                 w += 131072;                   // 128 KB
    unsigned int* rec = (unsigned int*)w;    w += (size_t)NB_T * CAP * 4;   // 9.6 MB
    uint2* rec2 = (uint2*)w;                 w += (size_t)NB_T * CAP2 * 8;  // 8.8 MB
    int* cur = (int*)w;                      w += 4096;   // [0..391)=d0, [391..782)=edges

    const size_t need = (size_t)(w - (char*)d_ws);
    const int use_sorted = (ws_size >= need) ? 1 : 0;
    int* cur2 = cur + NB_T;

    hipMemsetAsync(cur, 0, 2 * NB_T * sizeof(int), stream);
    prep_bin<<<NB_T, 256, 0, stream>>>(Wq, Wk, Wb, d0, rec, cur,
                                       edge_index, rec2, cur2, use_sorted);
    proj_mfma<<<(N_NODES + 63) / 64, 256, 0, stream>>>(x, Wb, bq, bk, qk8);
    if (use_sorted)
        edge_compute<<<NB_T * BPB2, 256, 0, stream>>>(qk8, rec2, cur2, out);
    else
        edge_direct<<<N_EDGES / 64, 256, 0, stream>>>(qk8, edge_index, out);
    phase_scatter<<<NB_T, 1024, 0, stream>>>(rec, cur, out);
}

// Round 9
// 205.891 us; speedup vs baseline: 1.1475x; 1.0643x over previous
//
#include <hip/hip_runtime.h>
#include <hip/hip_bf16.h>

#define N_NODES 50000
#define N_EDGES 800000
#define DIM 256      // input feature dim = K
#define QKDIM 256    // packed q|k per node (fp8: 256 B/row)
#define NB_T  391    // target buckets: d0 >> 7 (128 nodes per bucket)
#define CAP   8192   // per-bucket record capacity (mean 4092, sigma ~64)
#define ITEMS (2 * N_EDGES)
#define IPB   4096   // items per prep_bin block (391 * 4096 >= 1.6M)
// pre = (0.5/H) * sum_A (q_s k_d + q_d k_s) = (full rotated 256-dot)/16

typedef __bf16 bfrag  __attribute__((ext_vector_type(8)));
typedef __bf16 bf4    __attribute__((ext_vector_type(4)));
typedef float  ffrag  __attribute__((ext_vector_type(4)));
typedef float  f2     __attribute__((ext_vector_type(2)));
typedef float  f4v    __attribute__((ext_vector_type(4)));

#define EP_PITCH 272   // epilogue LDS byte pitch (256+16)

// ---------------- prep_bin: W' fp32->bf16 + bin d0 items by target bucket ----
// Binning: per-block LDS hist -> one global chunk-reservation atomic per
// (block,bucket) (~150K atomics total) -> packed records (local<<20 | edge).
__global__ __launch_bounds__(256) void prep_bin(
    const float* __restrict__ Wq, const float* __restrict__ Wk,
    __bf16* __restrict__ Wb,
    const int* __restrict__ d0, unsigned int* __restrict__ rec,
    int* __restrict__ cur)
{
    __shared__ int lcnt[NB_T];
    __shared__ int lbase[NB_T];
    const int tid = threadIdx.x;
    const int gtid = blockIdx.x * 256 + tid;

    // ---- W convert (first 16384 gtids cover 65536 floats) ----
    const int i4 = gtid * 4;
    if (i4 < 65536) {
        const float* s = (i4 < 32768) ? (Wq + i4) : (Wk + (i4 - 32768));
        const float4 v = *(const float4*)s;
        bf4 o;
        o[0] = (__bf16)v.x; o[1] = (__bf16)v.y; o[2] = (__bf16)v.z; o[3] = (__bf16)v.w;
        *(bf4*)(Wb + i4) = o;
    }

    // ---- pass 1: count this block's items per bucket ----
    for (int b = tid; b < NB_T; b += 256) lcnt[b] = 0;
    __syncthreads();
    const int base = blockIdx.x * IPB;
    int tg[16];
    #pragma unroll
    for (int r = 0; r < 16; ++r) {
        const int i = base + r * 256 + tid;
        tg[r] = (i < ITEMS) ? d0[i] : -1;
        if (tg[r] >= 0) atomicAdd(&lcnt[tg[r] >> 7], 1);
    }
    __syncthreads();

    // ---- reserve contiguous chunks in each bucket ----
    for (int b = tid; b < NB_T; b += 256) {
        const int c = lcnt[b];
        lbase[b] = c ? atomicAdd(&cur[b], c) : 0;
    }
    __syncthreads();
    for (int b = tid; b < NB_T; b += 256) lcnt[b] = 0;   // reuse as offset
    __syncthreads();

    // ---- pass 2: write packed records ----
    #pragma unroll
    for (int r = 0; r < 16; ++r) {
        if (tg[r] >= 0) {
            const int i = base + r * 256 + tid;
            const int b = tg[r] >> 7;
            const int off = atomicAdd(&lcnt[b], 1);
            rec[(size_t)b * CAP + lbase[b] + off] =
                ((unsigned int)(tg[r] & 127) << 20) | (unsigned int)(i >> 1);
        }
    }
}

// ---------------- Projection via MFMA bf16 (unchanged, known-good) ----------
__global__ __launch_bounds__(256) void proj_mfma(
    const float* __restrict__ x,
    const __bf16* __restrict__ Wb,
    const float* __restrict__ bq, const float* __restrict__ bk,
    unsigned char* __restrict__ qk8)
{
    __shared__ __bf16 As[64 * 256];   // 32 KB, fragment-order; reused by epilogue

    const int tid  = threadIdx.x;
    const int wv   = tid >> 6;
    const int lane = tid & 63;
    const int m    = lane & 15;
    const int q    = lane >> 4;
    const int mbase = blockIdx.x * 64;

    {
        const int srow = tid >> 2;
        const int c4   = tid & 3;
        int grow = mbase + srow;
        grow = grow < N_NODES ? grow : N_NODES - 1;
        const float* xp = x + (size_t)grow * DIM;
        const int mt_ = srow >> 4, m_ = srow & 15;
        #pragma unroll
        for (int i = 0; i < 16; ++i) {
            const int k = c4 * 4 + 16 * i;
            const f4v v = __builtin_nontemporal_load((const f4v*)(xp + k));
            bf4 o;
            o[0] = (__bf16)v[0]; o[1] = (__bf16)v[1];
            o[2] = (__bf16)v[2]; o[3] = (__bf16)v[3];
            const int seg = (k >> 5) * 4 + mt_;
            const int ln  = ((k >> 3) & 3) * 16 + m_;
            *(bf4*)(As + seg * 512 + ln * 8 + (k & 7)) = o;
        }
    }
    __syncthreads();

    ffrag acc[4][4] = {};

    #pragma unroll
    for (int h = 0; h < 2; ++h) {
        bfrag b[4][4];
        #pragma unroll
        for (int sp = 0; sp < 4; ++sp)
            #pragma unroll
            for (int nt = 0; nt < 4; ++nt) {
                const int col = wv * 64 + nt * 16 + m;
                b[sp][nt] = *(const bfrag*)(Wb + (size_t)col * DIM
                                            + 32 * (4 * h + sp) + 8 * q);
            }
        #pragma unroll
        for (int sp = 0; sp < 4; ++sp) {
            bfrag a[4];
            #pragma unroll
            for (int mt = 0; mt < 4; ++mt)
                a[mt] = *(const bfrag*)(As + ((4 * h + sp) * 4 + mt) * 512 + lane * 8);
            #pragma unroll
            for (int mt = 0; mt < 4; ++mt)
                #pragma unroll
                for (int nt = 0; nt < 4; ++nt)
                    acc[mt][nt] = __builtin_amdgcn_mfma_f32_16x16x32_bf16(
                                      a[mt], b[sp][nt], acc[mt][nt], 0, 0, 0);
        }
    }

    __syncthreads();
    unsigned char* ep = (unsigned char*)As;
    #pragma unroll
    for (int nt = 0; nt < 4; ++nt) {
        const int col  = wv * 64 + nt * 16 + m;
        const float bias = (col < 128) ? bq[col] : bk[col - 128];
        #pragma unroll
        for (int mt = 0; mt < 4; ++mt) {
            #pragma unroll
            for (int r = 0; r < 4; ++r) {
                const int rl = mt * 16 + q * 4 + r;
                const float v = acc[mt][nt][r] + bias;
                const int pk = __builtin_amdgcn_cvt_pk_fp8_f32(v, v, 0, false);
                ep[rl * EP_PITCH + col] = (unsigned char)(pk & 0xFF);
            }
        }
    }
    __syncthreads();
    {
        const int rl = tid >> 2;
        const int ch = tid & 3;
        const int grow = mbase + rl;
        if (grow < N_NODES) {
            const uint4* s4 = (const uint4*)(ep + rl * EP_PITCH + ch * 64);
            const uint4 t0 = s4[0], t1 = s4[1], t2 = s4[2], t3 = s4[3];
            uint4* g = (uint4*)(qk8 + (size_t)grow * QKDIM + ch * 64);
            g[0] = t0; g[1] = t1; g[2] = t2; g[3] = t3;
        }
    }
}

// ---------------- Edge scoring: COALESCED gather + dot + exp, NO atomics ----
// 4 lanes per edge, 16 edges per wave. NEW lane layout: for load i, lane j
// reads 16B at src byte 64i+16j -> the 4 lanes of a group cover ONE 64B line
// per instruction (16 lines/wave-instr, the coalescing floor) instead of the
// old 64 (lane j owned bytes [64j,+64) -> stride-64 within each instr).
// Rotated dst side: byte t pairs with (t+128)&255 -> load i reads dst line
// ((i+2)&3), lane offset 16j. Same math, same shfl reduce.  [R4-verified]
__global__ __launch_bounds__(256) void edge_compute(
    const unsigned char* __restrict__ qk8,
    const int* __restrict__ edge_index,   // [2][E]
    float* __restrict__ out)              // writes diagA1 = out[N..N+E)
{
    const int wave = (blockIdx.x * blockDim.x + threadIdx.x) >> 6;
    const int lane = threadIdx.x & 63;
    const int g = lane >> 2;              // edge within wave (0..15)
    const int j = lane & 3;               // lane within edge
    const int e = wave * 16 + g;          // 800000 = 50000*16, no tail

    const int src = __builtin_nontemporal_load(edge_index + e);
    const int dst = __builtin_nontemporal_load(edge_index + N_EDGES + e);

    const uint4* rs = (const uint4*)(qk8 + (size_t)src * QKDIM);
    const uint4* rd = (const uint4*)(qk8 + (size_t)dst * QKDIM);

    // load i: src uint4 index 4i+j (byte 64i+16j); dst uint4 4*((i+2)&3)+j
    uint4 a[4], b[4];
    #pragma unroll
    for (int i = 0; i < 4; ++i) a[i] = rs[4 * i + j];
    #pragma unroll
    for (int i = 0; i < 4; ++i) b[i] = rd[4 * ((i + 2) & 3) + j];

    f2 acc = {0.f, 0.f};
    #pragma unroll
    for (int i = 0; i < 4; ++i) {
        const unsigned int* ua = (const unsigned int*)&a[i];
        const unsigned int* ub = (const unsigned int*)&b[i];
        #pragma unroll
        for (int t = 0; t < 4; ++t) {
            const f2 x0 = __builtin_amdgcn_cvt_pk_f32_fp8(ua[t], false);
            const f2 y0 = __builtin_amdgcn_cvt_pk_f32_fp8(ub[t], false);
            const f2 x1 = __builtin_amdgcn_cvt_pk_f32_fp8(ua[t], true);
            const f2 y1 = __builtin_amdgcn_cvt_pk_f32_fp8(ub[t], true);
            acc += x0 * y0;
            acc += x1 * y1;
        }
    }
    float p = acc[0] + acc[1];

    // reduce across the 4 lanes of this edge group
    p += __shfl_xor(p, 1, 64);
    p += __shfl_xor(p, 2, 64);

    if (j == 0)
        out[N_NODES + e] = __expf(p * 0.0625f);   // /16 = 0.5 * mean over 8 heads
}

// ---------------- phase_scatter: per-bucket LDS aggregation -> plain stores -
// Block b owns nodes [128b, 128b+128): reads its bucket's records, gathers
// val[e] from diagA1 (L2-resident), LDS-atomicAdd, then unique-writer stores.
// Zero global atomics; out[0..N) needs no pre-zeroing.
__global__ __launch_bounds__(1024) void phase_scatter(
    const unsigned int* __restrict__ rec, const int* __restrict__ cur,
    float* __restrict__ out)
{
    __shared__ float acc[128];
    const int b = blockIdx.x;
    const int tid = threadIdx.x;
    if (tid < 128) acc[tid] = 0.f;
    __syncthreads();

    const int cnt = cur[b];
    const unsigned int* rb = rec + (size_t)b * CAP;
    for (int i = tid; i < cnt; i += 1024) {
        const unsigned int r = rb[i];
        const float v = out[N_NODES + (r & 0xFFFFF)];
        atomicAdd(&acc[r >> 20], v);
    }
    __syncthreads();

    if (tid < 128) {
        const int n = b * 128 + tid;
        if (n < N_NODES) out[n] = acc[tid];
    }
}

extern "C" void kernel_launch(void* const* d_in, const int* in_sizes, int n_in,
                              void* d_out, int out_size, void* d_ws, size_t ws_size,
                              hipStream_t stream) {
    const float* x  = (const float*)d_in[0];
    const float* Wq = (const float*)d_in[1];
    const float* bq = (const float*)d_in[2];
    const float* Wk = (const float*)d_in[3];
    const float* bk = (const float*)d_in[4];
    const int* edge_index = (const int*)d_in[5];
    const int* d0 = (const int*)d_in[6] + 2 * N_EDGES;  // row 1 of d0_index
    float* out = (float*)d_out;

    char* w = (char*)d_ws;
    unsigned char* qk8 = (unsigned char*)w;  w += (size_t)N_NODES * QKDIM;  // 12.8 MB
    __bf16* Wb = (__bf16*)w;                 w += 131072;                   // 128 KB
    unsigned int* rec = (unsigned int*)w;    w += (size_t)NB_T * CAP * 4;   // 12.8 MB
    int* cur = (int*)w;                      w += 2048;

    hipMemsetAsync(cur, 0, NB_T * sizeof(int), stream);
    prep_bin<<<NB_T, 256, 0, stream>>>(Wq, Wk, Wb, d0, rec, cur);
    proj_mfma<<<(N_NODES + 63) / 64, 256, 0, stream>>>(x, Wb, bq, bk, qk8);
    edge_compute<<<N_EDGES / 64, 256, 0, stream>>>(qk8, edge_index, out);
    phase_scatter<<<NB_T, 1024, 0, stream>>>(rec, cur, out);
}